// Round 1
// baseline (454.506 us; speedup 1.0000x reference)
//
#include <hip/hip_runtime.h>
#include <hip/hip_bf16.h>

#define B_ 8
#define C_ 192
#define G_ 256
#define E_ 384
#define R_ 4
#define T_ 8192
#define L_ 3
#define K_ 3

typedef __attribute__((ext_vector_type(4))) float f32x4;
typedef __attribute__((ext_vector_type(8))) short bf16x8;

static __device__ __forceinline__ float gelu_f(float x) {
    return 0.5f * x * (1.0f + erff(x * 0.70710678118654752f));
}

// ---------------- adapter projections: a = g2 @ w.T + bias -------------
// w: (L*rows, G), out layout [L][B][rows]
__global__ __launch_bounds__(256) void adapter_kernel(
    const float* __restrict__ g2, const float* __restrict__ w,
    const float* __restrict__ bias, float* __restrict__ out, int rows)
{
    int idx = blockIdx.x * 256 + threadIdx.x;
    int total = L_ * rows * B_;
    if (idx >= total) return;
    int bb = idx & 7;
    int lr = idx >> 3;
    int l = lr / rows, rr = lr % rows;
    const float4* wr = (const float4*)(w + (size_t)lr * G_);
    const float4* gb = (const float4*)(g2 + (size_t)bb * G_);
    float s = bias[lr];
    for (int g = 0; g < G_ / 4; ++g) {
        float4 a = gb[g], b = wr[g];
        s = fmaf(a.x, b.x, s); s = fmaf(a.y, b.y, s);
        s = fmaf(a.z, b.z, s); s = fmaf(a.w, b.w, s);
    }
    out[((size_t)l * B_ + bb) * rows + rr] = s;
}

// ---------------- effective weights ------------------------------------
// W1eff[l][b][e][c] = p1_w[l][e][c] + sum_r ain[c*R+r]*aout[r*E+e]
__global__ __launch_bounds__(256) void build_w1_kernel(
    const float* __restrict__ wm, const float* __restrict__ ain,
    const float* __restrict__ aout, __hip_bfloat16* __restrict__ out)
{
    int idx = blockIdx.x * 256 + threadIdx.x;
    if (idx >= L_ * B_ * E_ * C_) return;
    int c = idx % C_;
    int e = (idx / C_) % E_;
    int b = (idx / (C_ * E_)) % B_;
    int l = idx / (C_ * E_ * B_);
    float v = wm[((size_t)l * E_ + e) * C_ + c];
    const float* ai = ain + ((size_t)l * B_ + b) * (C_ * R_);
    const float* ao = aout + ((size_t)l * B_ + b) * (R_ * E_);
#pragma unroll
    for (int r = 0; r < R_; ++r) v = fmaf(ai[c * R_ + r], ao[r * E_ + e], v);
    out[idx] = __float2bfloat16(v);
}

// W2eff[l][b][c][e] = p2_w[l][c][e] + sum_r ain[e*R+r]*aout[r*C+c]
__global__ __launch_bounds__(256) void build_w2_kernel(
    const float* __restrict__ wm, const float* __restrict__ ain,
    const float* __restrict__ aout, __hip_bfloat16* __restrict__ out)
{
    int idx = blockIdx.x * 256 + threadIdx.x;
    if (idx >= L_ * B_ * C_ * E_) return;
    int e = idx % E_;
    int c = (idx / E_) % C_;
    int b = (idx / (C_ * E_)) % B_;
    int l = idx / (C_ * E_ * B_);
    float v = wm[((size_t)l * C_ + c) * E_ + e];
    const float* ai = ain + ((size_t)l * B_ + b) * (E_ * R_);
    const float* ao = aout + ((size_t)l * B_ + b) * (R_ * C_);
#pragma unroll
    for (int r = 0; r < R_; ++r) v = fmaf(ai[e * R_ + r], ao[r * C_ + c], v);
    out[idx] = __float2bfloat16(v);
}

// ---------------- transpose (B,C,T) -> (B,T,C) with mask ---------------
__global__ __launch_bounds__(256) void transpose_in_kernel(
    const float* __restrict__ x, const float* __restrict__ mask,
    float* __restrict__ xw)
{
    __shared__ float tile[64][65];
    int b = blockIdx.z, c0 = blockIdx.y * 64, t0 = blockIdx.x * 64;
    for (int i = threadIdx.x; i < 4096; i += 256) {
        int r = i >> 6, col = i & 63;
        tile[r][col] = x[((size_t)b * C_ + c0 + r) * T_ + t0 + col] *
                       mask[(size_t)b * T_ + t0 + col];
    }
    __syncthreads();
    for (int i = threadIdx.x; i < 4096; i += 256) {
        int r = i >> 6, col = i & 63;
        xw[((size_t)b * T_ + t0 + r) * C_ + c0 + col] = tile[col][r];
    }
}

// ---------------- transpose (B,T,C) -> (B,C,T) -------------------------
__global__ __launch_bounds__(256) void transpose_out_kernel(
    const float* __restrict__ xw, float* __restrict__ out)
{
    __shared__ float tile[64][65];
    int b = blockIdx.z, c0 = blockIdx.y * 64, t0 = blockIdx.x * 64;
    for (int i = threadIdx.x; i < 4096; i += 256) {
        int r = i >> 6, col = i & 63;
        tile[r][col] = xw[((size_t)b * T_ + t0 + r) * C_ + c0 + col];
    }
    __syncthreads();
    for (int i = threadIdx.x; i < 4096; i += 256) {
        int r = i >> 6, col = i & 63;
        out[((size_t)b * C_ + c0 + r) * T_ + t0 + col] = tile[col][r];
    }
}

// ---------------- dconv (causal, dilated, K=3) + LayerNorm(C) + mask ---
// xw: (B,T,C) f32, h out: (B,T,C) bf16
__global__ __launch_bounds__(256) void dconv_ln_kernel(
    const float* __restrict__ xw, const float* __restrict__ dw,
    const float* __restrict__ db, const float* __restrict__ gamma,
    const float* __restrict__ beta, const float* __restrict__ mask,
    __hip_bfloat16* __restrict__ h, int dil)
{
    int b = blockIdx.y;
    int t0 = blockIdx.x * 64;
    int lane = threadIdx.x & 63;
    int wv = threadIdx.x >> 6;
    float w0[3], w1[3], w2[3], bia[3], ga[3], be[3];
#pragma unroll
    for (int cc = 0; cc < 3; ++cc) {
        int c = lane + cc * 64;
        w0[cc] = dw[c * K_ + 0];
        w1[cc] = dw[c * K_ + 1];
        w2[cc] = dw[c * K_ + 2];
        bia[cc] = db[c]; ga[cc] = gamma[c]; be[cc] = beta[c];
    }
    for (int i = 0; i < 16; ++i) {
        int t = t0 + wv * 16 + i;
        const float* row0 = xw + ((size_t)b * T_ + t) * C_;
        float v[3];
#pragma unroll
        for (int cc = 0; cc < 3; ++cc) {
            int c = lane + cc * 64;
            float acc = fmaf(w0[cc], row0[c], bia[cc]);
            if (t - dil >= 0)     acc = fmaf(w1[cc], row0[c - dil * C_], acc);
            if (t - 2 * dil >= 0) acc = fmaf(w2[cc], row0[c - 2 * dil * C_], acc);
            v[cc] = acc;
        }
        float s = v[0] + v[1] + v[2];
        float sq = v[0] * v[0] + v[1] * v[1] + v[2] * v[2];
#pragma unroll
        for (int o = 32; o >= 1; o >>= 1) {
            s += __shfl_xor(s, o, 64);
            sq += __shfl_xor(sq, o, 64);
        }
        float mu = s * (1.0f / C_);
        float var = sq * (1.0f / C_) - mu * mu;
        float rs = rsqrtf(var + 1e-5f);
        float m = mask[(size_t)b * T_ + t];
        __hip_bfloat16* hrow = h + ((size_t)b * T_ + t) * C_;
#pragma unroll
        for (int cc = 0; cc < 3; ++cc) {
            int c = lane + cc * 64;
            float o = (fmaf((v[cc] - mu) * rs, ga[cc], be[cc])) * m;
            hrow[c] = __float2bfloat16(o);
        }
    }
}

// ---------------- fused W1@h + b1 -> gelu -> W2@. + b2 + residual ------
// h: (B,T,C) bf16; W1: (B,E,C) bf16; W2: (B,C,E) bf16; xw: (B,T,C) f32
__global__ __launch_bounds__(256, 2) void ffn_kernel(
    const __hip_bfloat16* __restrict__ h,
    const __hip_bfloat16* __restrict__ W1, const float* __restrict__ b1,
    const __hip_bfloat16* __restrict__ W2, const float* __restrict__ b2,
    float* __restrict__ xw)
{
    __shared__ __hip_bfloat16 Hs[64][C_ + 8];     // 25.6 KB
    __shared__ __hip_bfloat16 H1s[64][E_ + 8];    // 50.2 KB
    int b = blockIdx.y;
    int t0 = blockIdx.x * 64;
    int tid = threadIdx.x;
    int lane = tid & 63, wv = tid >> 6;
    int lhi = lane >> 4, llo = lane & 15;

    // stage h tile: 64 rows x 192 bf16
    {
        const __hip_bfloat16* src = h + ((size_t)b * T_ + t0) * C_;
#pragma unroll
        for (int it = 0; it < 6; ++it) {
            int idx = it * 256 + tid;
            int row = idx / 24;
            int col = (idx % 24) * 8;
            *(int4*)(&Hs[row][col]) = *(const int4*)(&src[(size_t)row * C_ + col]);
        }
    }
    __syncthreads();

    // GEMM1: rows e in [wv*96, wv*96+96), cols t 0..63
    f32x4 acc1[6][4];
#pragma unroll
    for (int mf = 0; mf < 6; ++mf)
#pragma unroll
        for (int nf = 0; nf < 4; ++nf) acc1[mf][nf] = (f32x4){0.f, 0.f, 0.f, 0.f};

    const __hip_bfloat16* w1b = W1 + (size_t)b * E_ * C_ + ((size_t)(wv * 96 + llo)) * C_ + lhi * 8;
#pragma unroll
    for (int kc = 0; kc < 6; ++kc) {
        bf16x8 bfr[4];
#pragma unroll
        for (int nf = 0; nf < 4; ++nf)
            bfr[nf] = *(const bf16x8*)(&Hs[nf * 16 + llo][kc * 32 + lhi * 8]);
#pragma unroll
        for (int mf = 0; mf < 6; ++mf) {
            bf16x8 af = *(const bf16x8*)(&w1b[(size_t)mf * 16 * C_ + kc * 32]);
#pragma unroll
            for (int nf = 0; nf < 4; ++nf)
                acc1[mf][nf] = __builtin_amdgcn_mfma_f32_16x16x32_bf16(af, bfr[nf], acc1[mf][nf], 0, 0, 0);
        }
    }

    // epilogue1: bias + gelu -> H1s (bf16)
#pragma unroll
    for (int mf = 0; mf < 6; ++mf) {
        int e0 = wv * 96 + mf * 16 + lhi * 4;
        float bb[4];
#pragma unroll
        for (int j = 0; j < 4; ++j) bb[j] = b1[e0 + j];
#pragma unroll
        for (int nf = 0; nf < 4; ++nf) {
            int row = nf * 16 + llo;
            union { __hip_bfloat16 h4[4]; int2 i2; } u;
#pragma unroll
            for (int j = 0; j < 4; ++j)
                u.h4[j] = __float2bfloat16(gelu_f(acc1[mf][nf][j] + bb[j]));
            *(int2*)(&H1s[row][e0]) = u.i2;
        }
    }
    __syncthreads();

    // GEMM2: rows c in [wv*48, wv*48+48), cols t 0..63
    f32x4 acc2[3][4];
#pragma unroll
    for (int mf = 0; mf < 3; ++mf)
#pragma unroll
        for (int nf = 0; nf < 4; ++nf) acc2[mf][nf] = (f32x4){0.f, 0.f, 0.f, 0.f};

    const __hip_bfloat16* w2b = W2 + (size_t)b * C_ * E_ + ((size_t)(wv * 48 + llo)) * E_ + lhi * 8;
#pragma unroll
    for (int kc = 0; kc < 12; ++kc) {
        bf16x8 bfr[4];
#pragma unroll
        for (int nf = 0; nf < 4; ++nf)
            bfr[nf] = *(const bf16x8*)(&H1s[nf * 16 + llo][kc * 32 + lhi * 8]);
#pragma unroll
        for (int mf = 0; mf < 3; ++mf) {
            bf16x8 af = *(const bf16x8*)(&w2b[(size_t)mf * 16 * E_ + kc * 32]);
#pragma unroll
            for (int nf = 0; nf < 4; ++nf)
                acc2[mf][nf] = __builtin_amdgcn_mfma_f32_16x16x32_bf16(af, bfr[nf], acc2[mf][nf], 0, 0, 0);
        }
    }

    // epilogue2: + b2 + residual, write back xw (f32)
#pragma unroll
    for (int mf = 0; mf < 3; ++mf) {
        int c0 = wv * 48 + mf * 16 + lhi * 4;
        float bb[4];
#pragma unroll
        for (int j = 0; j < 4; ++j) bb[j] = b2[c0 + j];
#pragma unroll
        for (int nf = 0; nf < 4; ++nf) {
            int t = t0 + nf * 16 + llo;
            float* p = xw + ((size_t)b * T_ + t) * C_ + c0;
            float4 r = *(float4*)p;
            r.x += acc2[mf][nf][0] + bb[0];
            r.y += acc2[mf][nf][1] + bb[1];
            r.z += acc2[mf][nf][2] + bb[2];
            r.w += acc2[mf][nf][3] + bb[3];
            *(float4*)p = r;
        }
    }
}

extern "C" void kernel_launch(void* const* d_in, const int* in_sizes, int n_in,
                              void* d_out, int out_size, void* d_ws, size_t ws_size,
                              hipStream_t stream) {
    const float* x        = (const float*)d_in[0];
    const float* x_mask   = (const float*)d_in[1];
    const float* g        = (const float*)d_in[2];   // (B,G,1) -> g2[b][g]
    const float* dconv_w  = (const float*)d_in[3];
    const float* dconv_b  = (const float*)d_in[4];
    const float* ln_gamma = (const float*)d_in[5];
    const float* ln_beta  = (const float*)d_in[6];
    const float* p1_w     = (const float*)d_in[7];
    const float* p1_b     = (const float*)d_in[8];
    const float* p1_ain_w = (const float*)d_in[9];
    const float* p1_ain_b = (const float*)d_in[10];
    const float* p1_aout_w= (const float*)d_in[11];
    const float* p1_aout_b= (const float*)d_in[12];
    const float* p2_w     = (const float*)d_in[13];
    const float* p2_b     = (const float*)d_in[14];
    const float* p2_ain_w = (const float*)d_in[15];
    const float* p2_ain_b = (const float*)d_in[16];
    const float* p2_aout_w= (const float*)d_in[17];
    const float* p2_aout_b= (const float*)d_in[18];

    char* ws = (char*)d_ws;
    size_t off = 0;
    float* xw = (float*)(ws + off);            off += (size_t)B_ * T_ * C_ * 4;
    __hip_bfloat16* hbuf = (__hip_bfloat16*)(ws + off); off += (size_t)B_ * T_ * C_ * 2;
    __hip_bfloat16* W1 = (__hip_bfloat16*)(ws + off);   off += (size_t)L_ * B_ * E_ * C_ * 2;
    __hip_bfloat16* W2 = (__hip_bfloat16*)(ws + off);   off += (size_t)L_ * B_ * C_ * E_ * 2;
    float* A1in  = (float*)(ws + off); off += (size_t)L_ * B_ * C_ * R_ * 4;
    float* A1out = (float*)(ws + off); off += (size_t)L_ * B_ * R_ * E_ * 4;
    float* A2in  = (float*)(ws + off); off += (size_t)L_ * B_ * E_ * R_ * 4;
    float* A2out = (float*)(ws + off); off += (size_t)L_ * B_ * R_ * C_ * 4;

    adapter_kernel<<<(L_ * C_ * R_ * B_ + 255) / 256, 256, 0, stream>>>(g, p1_ain_w, p1_ain_b, A1in, C_ * R_);
    adapter_kernel<<<(L_ * E_ * R_ * B_ + 255) / 256, 256, 0, stream>>>(g, p1_aout_w, p1_aout_b, A1out, E_ * R_);
    adapter_kernel<<<(L_ * E_ * R_ * B_ + 255) / 256, 256, 0, stream>>>(g, p2_ain_w, p2_ain_b, A2in, E_ * R_);
    adapter_kernel<<<(L_ * C_ * R_ * B_ + 255) / 256, 256, 0, stream>>>(g, p2_aout_w, p2_aout_b, A2out, C_ * R_);
    build_w1_kernel<<<(L_ * B_ * E_ * C_ + 255) / 256, 256, 0, stream>>>(p1_w, A1in, A1out, W1);
    build_w2_kernel<<<(L_ * B_ * C_ * E_ + 255) / 256, 256, 0, stream>>>(p2_w, A2in, A2out, W2);

    transpose_in_kernel<<<dim3(T_ / 64, C_ / 64, B_), 256, 0, stream>>>(x, x_mask, xw);

    const int DILS[3] = {1, 3, 9};
    for (int l = 0; l < L_; ++l) {
        dconv_ln_kernel<<<dim3(T_ / 64, B_), 256, 0, stream>>>(
            xw, dconv_w + l * C_ * K_, dconv_b + l * C_,
            ln_gamma + l * C_, ln_beta + l * C_, x_mask, hbuf, DILS[l]);
        ffn_kernel<<<dim3(T_ / 64, B_), 256, 0, stream>>>(
            hbuf, W1 + (size_t)l * B_ * E_ * C_, p1_b + l * E_,
            W2 + (size_t)l * B_ * C_ * E_, p2_b + l * C_, xw);
    }

    transpose_out_kernel<<<dim3(T_ / 64, C_ / 64, B_), 256, 0, stream>>>(xw, (float*)d_out);
}

// Round 2
// 413.699 us; speedup vs baseline: 1.0986x; 1.0986x over previous
//
#include <hip/hip_runtime.h>
#include <hip/hip_bf16.h>

#define B_ 8
#define C_ 192
#define G_ 256
#define E_ 384
#define R_ 4
#define T_ 8192
#define L_ 3
#define K_ 3

typedef __attribute__((ext_vector_type(4))) float f32x4;
typedef __attribute__((ext_vector_type(8))) short bf16x8;

// tanh-form GELU: max abs err vs erf-form ~1e-3, well under bf16 noise.
static __device__ __forceinline__ float gelu_fast(float x) {
    float z = 0.7978845608028654f * fmaf(0.044715f * x, x * x, x);
    float e = __expf(2.0f * z);
    float t = 1.0f - 2.0f / (e + 1.0f);   // tanh(z)
    return 0.5f * x * (1.0f + t);
}

// ---------------- adapter projections: a = g2 @ w.T + bias -------------
__global__ __launch_bounds__(256) void adapter_kernel(
    const float* __restrict__ g2, const float* __restrict__ w,
    const float* __restrict__ bias, float* __restrict__ out, int rows)
{
    int idx = blockIdx.x * 256 + threadIdx.x;
    int total = L_ * rows * B_;
    if (idx >= total) return;
    int bb = idx & 7;
    int lr = idx >> 3;
    int l = lr / rows, rr = lr % rows;
    const float4* wr = (const float4*)(w + (size_t)lr * G_);
    const float4* gb = (const float4*)(g2 + (size_t)bb * G_);
    float s = bias[lr];
    for (int g = 0; g < G_ / 4; ++g) {
        float4 a = gb[g], b = wr[g];
        s = fmaf(a.x, b.x, s); s = fmaf(a.y, b.y, s);
        s = fmaf(a.z, b.z, s); s = fmaf(a.w, b.w, s);
    }
    out[((size_t)l * B_ + bb) * rows + rr] = s;
}

// ---------------- effective weights ------------------------------------
__global__ __launch_bounds__(256) void build_w1_kernel(
    const float* __restrict__ wm, const float* __restrict__ ain,
    const float* __restrict__ aout, __hip_bfloat16* __restrict__ out)
{
    int idx = blockIdx.x * 256 + threadIdx.x;
    if (idx >= L_ * B_ * E_ * C_) return;
    int c = idx % C_;
    int e = (idx / C_) % E_;
    int b = (idx / (C_ * E_)) % B_;
    int l = idx / (C_ * E_ * B_);
    float v = wm[((size_t)l * E_ + e) * C_ + c];
    const float* ai = ain + ((size_t)l * B_ + b) * (C_ * R_);
    const float* ao = aout + ((size_t)l * B_ + b) * (R_ * E_);
#pragma unroll
    for (int r = 0; r < R_; ++r) v = fmaf(ai[c * R_ + r], ao[r * E_ + e], v);
    out[idx] = __float2bfloat16(v);
}

__global__ __launch_bounds__(256) void build_w2_kernel(
    const float* __restrict__ wm, const float* __restrict__ ain,
    const float* __restrict__ aout, __hip_bfloat16* __restrict__ out)
{
    int idx = blockIdx.x * 256 + threadIdx.x;
    if (idx >= L_ * B_ * C_ * E_) return;
    int e = idx % E_;
    int c = (idx / E_) % C_;
    int b = (idx / (C_ * E_)) % B_;
    int l = idx / (C_ * E_ * B_);
    float v = wm[((size_t)l * C_ + c) * E_ + e];
    const float* ai = ain + ((size_t)l * B_ + b) * (E_ * R_);
    const float* ao = aout + ((size_t)l * B_ + b) * (R_ * C_);
#pragma unroll
    for (int r = 0; r < R_; ++r) v = fmaf(ai[e * R_ + r], ao[r * C_ + c], v);
    out[idx] = __float2bfloat16(v);
}

// ---------------- transpose (B,C,T) -> (B,T,C) with mask ---------------
__global__ __launch_bounds__(256) void transpose_in_kernel(
    const float* __restrict__ x, const float* __restrict__ mask,
    float* __restrict__ xw)
{
    __shared__ float tile[64][65];
    int b = blockIdx.z, c0 = blockIdx.y * 64, t0 = blockIdx.x * 64;
    for (int i = threadIdx.x; i < 4096; i += 256) {
        int r = i >> 6, col = i & 63;
        tile[r][col] = x[((size_t)b * C_ + c0 + r) * T_ + t0 + col] *
                       mask[(size_t)b * T_ + t0 + col];
    }
    __syncthreads();
    for (int i = threadIdx.x; i < 4096; i += 256) {
        int r = i >> 6, col = i & 63;
        xw[((size_t)b * T_ + t0 + r) * C_ + c0 + col] = tile[col][r];
    }
}

// ---------------- transpose (B,T,C) -> (B,C,T) -------------------------
__global__ __launch_bounds__(256) void transpose_out_kernel(
    const float* __restrict__ xw, float* __restrict__ out)
{
    __shared__ float tile[64][65];
    int b = blockIdx.z, c0 = blockIdx.y * 64, t0 = blockIdx.x * 64;
    for (int i = threadIdx.x; i < 4096; i += 256) {
        int r = i >> 6, col = i & 63;
        tile[r][col] = xw[((size_t)b * T_ + t0 + r) * C_ + c0 + col];
    }
    __syncthreads();
    for (int i = threadIdx.x; i < 4096; i += 256) {
        int r = i >> 6, col = i & 63;
        out[((size_t)b * C_ + c0 + r) * T_ + t0 + col] = tile[col][r];
    }
}

// ---------------- fully fused layer: dconv+LN+mask -> GEMM1 -> GELU ----
// ---------------- -> GEMM2 -> +bias +residual --------------------------
// xin: (B,T,C) f32 (masked layer input); xout: (B,T,C) f32
// W1: (B,E,C) bf16; W2: (B,C,E) bf16
__global__ __launch_bounds__(512, 4) void ffn_fused_kernel(
    const float* __restrict__ xin, float* __restrict__ xout,
    const float* __restrict__ dw, const float* __restrict__ db,
    const float* __restrict__ gamma, const float* __restrict__ beta,
    const float* __restrict__ mask,
    const __hip_bfloat16* __restrict__ W1, const float* __restrict__ b1,
    const __hip_bfloat16* __restrict__ W2, const float* __restrict__ b2,
    int dil)
{
    __shared__ __hip_bfloat16 Hs[64][C_ + 8];     // 25.6 KB
    __shared__ __hip_bfloat16 H1s[64][E_ + 8];    // 50.2 KB
    int b = blockIdx.y;
    int t0 = blockIdx.x * 64;
    int tid = threadIdx.x;
    int w = tid >> 6, lane = tid & 63;
    int lhi = lane >> 4, llo = lane & 15;

    // ---- staging phase: dconv (causal dilated K=3) + LayerNorm + mask ----
    {
        float cw0[3], cw1[3], cw2[3], bia[3], ga[3], be[3];
#pragma unroll
        for (int cc = 0; cc < 3; ++cc) {
            int c = cc * 64 + lane;
            cw0[cc] = dw[c * K_ + 0];
            cw1[cc] = dw[c * K_ + 1];
            cw2[cc] = dw[c * K_ + 2];
            bia[cc] = db[c]; ga[cc] = gamma[c]; be[cc] = beta[c];
        }
#pragma unroll
        for (int i = 0; i < 8; ++i) {
            int t = t0 + w * 8 + i;
            const float* r0 = xin + ((size_t)b * T_ + t) * C_;
            bool has1 = (t - dil) >= 0;
            bool has2 = (t - 2 * dil) >= 0;
            float v[3];
#pragma unroll
            for (int cc = 0; cc < 3; ++cc) {
                int c = cc * 64 + lane;
                float acc = fmaf(cw0[cc], r0[c], bia[cc]);
                if (has1) acc = fmaf(cw1[cc], r0[c - dil * C_], acc);
                if (has2) acc = fmaf(cw2[cc], r0[c - 2 * dil * C_], acc);
                v[cc] = acc;
            }
            float s = v[0] + v[1] + v[2];
            float sq = fmaf(v[0], v[0], fmaf(v[1], v[1], v[2] * v[2]));
#pragma unroll
            for (int o = 32; o >= 1; o >>= 1) {
                s += __shfl_xor(s, o, 64);
                sq += __shfl_xor(sq, o, 64);
            }
            float mu = s * (1.0f / C_);
            float var = sq * (1.0f / C_) - mu * mu;
            float rs = rsqrtf(var + 1e-5f);
            float m = mask[(size_t)b * T_ + t];
#pragma unroll
            for (int cc = 0; cc < 3; ++cc) {
                int c = cc * 64 + lane;
                Hs[w * 8 + i][c] =
                    __float2bfloat16(fmaf((v[cc] - mu) * rs, ga[cc], be[cc]) * m);
            }
        }
    }
    __syncthreads();

    // ---- GEMM1: wave w owns e in [w*48, w*48+48), t cols 0..63 ----
    f32x4 acc1[3][4];
#pragma unroll
    for (int mf = 0; mf < 3; ++mf)
#pragma unroll
        for (int nf = 0; nf < 4; ++nf) acc1[mf][nf] = (f32x4){0.f, 0.f, 0.f, 0.f};

    {
        const __hip_bfloat16* w1p =
            W1 + (size_t)b * E_ * C_ + ((size_t)(w * 48 + llo)) * C_ + lhi * 8;
#pragma unroll
        for (int kc = 0; kc < 6; ++kc) {
            bf16x8 bfr[4];
#pragma unroll
            for (int nf = 0; nf < 4; ++nf)
                bfr[nf] = *(const bf16x8*)(&Hs[nf * 16 + llo][kc * 32 + lhi * 8]);
#pragma unroll
            for (int mf = 0; mf < 3; ++mf) {
                bf16x8 af = *(const bf16x8*)(&w1p[(size_t)mf * 16 * C_ + kc * 32]);
#pragma unroll
                for (int nf = 0; nf < 4; ++nf)
                    acc1[mf][nf] = __builtin_amdgcn_mfma_f32_16x16x32_bf16(
                        af, bfr[nf], acc1[mf][nf], 0, 0, 0);
            }
        }
    }

    // ---- epilogue1: bias + fast GELU -> H1s ----
#pragma unroll
    for (int mf = 0; mf < 3; ++mf) {
        int e0 = w * 48 + mf * 16 + lhi * 4;
        float bb[4];
#pragma unroll
        for (int j = 0; j < 4; ++j) bb[j] = b1[e0 + j];
#pragma unroll
        for (int nf = 0; nf < 4; ++nf) {
            int row = nf * 16 + llo;
            union { __hip_bfloat16 h4[4]; int2 i2; } u;
#pragma unroll
            for (int j = 0; j < 4; ++j)
                u.h4[j] = __float2bfloat16(gelu_fast(acc1[mf][nf][j] + bb[j]));
            *(int2*)(&H1s[row][e0]) = u.i2;
        }
    }
    __syncthreads();

    // ---- GEMM2: wave (cq = w&3, th = w>>2): c in [cq*48,+48), t in [th*32,+32) ----
    int cq = w & 3, th = w >> 2;
    f32x4 acc2[3][2];
#pragma unroll
    for (int mf = 0; mf < 3; ++mf)
#pragma unroll
        for (int nf = 0; nf < 2; ++nf) acc2[mf][nf] = (f32x4){0.f, 0.f, 0.f, 0.f};

    {
        const __hip_bfloat16* w2p =
            W2 + (size_t)b * C_ * E_ + ((size_t)(cq * 48 + llo)) * E_ + lhi * 8;
#pragma unroll
        for (int kc = 0; kc < 12; ++kc) {
            bf16x8 bfr[2];
#pragma unroll
            for (int nf = 0; nf < 2; ++nf)
                bfr[nf] = *(const bf16x8*)(&H1s[th * 32 + nf * 16 + llo][kc * 32 + lhi * 8]);
#pragma unroll
            for (int mf = 0; mf < 3; ++mf) {
                bf16x8 af = *(const bf16x8*)(&w2p[(size_t)mf * 16 * E_ + kc * 32]);
#pragma unroll
                for (int nf = 0; nf < 2; ++nf)
                    acc2[mf][nf] = __builtin_amdgcn_mfma_f32_16x16x32_bf16(
                        af, bfr[nf], acc2[mf][nf], 0, 0, 0);
            }
        }
    }

    // ---- epilogue2: + b2 + residual (from xin), write xout ----
#pragma unroll
    for (int mf = 0; mf < 3; ++mf) {
        int c0 = cq * 48 + mf * 16 + lhi * 4;
        float bb[4];
#pragma unroll
        for (int j = 0; j < 4; ++j) bb[j] = b2[c0 + j];
#pragma unroll
        for (int nf = 0; nf < 2; ++nf) {
            int t = t0 + th * 32 + nf * 16 + llo;
            const float* pr = xin + ((size_t)b * T_ + t) * C_ + c0;
            float* po = xout + ((size_t)b * T_ + t) * C_ + c0;
            float4 r = *(const float4*)pr;
            r.x += acc2[mf][nf][0] + bb[0];
            r.y += acc2[mf][nf][1] + bb[1];
            r.z += acc2[mf][nf][2] + bb[2];
            r.w += acc2[mf][nf][3] + bb[3];
            *(float4*)po = r;
        }
    }
}

extern "C" void kernel_launch(void* const* d_in, const int* in_sizes, int n_in,
                              void* d_out, int out_size, void* d_ws, size_t ws_size,
                              hipStream_t stream) {
    const float* x        = (const float*)d_in[0];
    const float* x_mask   = (const float*)d_in[1];
    const float* g        = (const float*)d_in[2];
    const float* dconv_w  = (const float*)d_in[3];
    const float* dconv_b  = (const float*)d_in[4];
    const float* ln_gamma = (const float*)d_in[5];
    const float* ln_beta  = (const float*)d_in[6];
    const float* p1_w     = (const float*)d_in[7];
    const float* p1_b     = (const float*)d_in[8];
    const float* p1_ain_w = (const float*)d_in[9];
    const float* p1_ain_b = (const float*)d_in[10];
    const float* p1_aout_w= (const float*)d_in[11];
    const float* p1_aout_b= (const float*)d_in[12];
    const float* p2_w     = (const float*)d_in[13];
    const float* p2_b     = (const float*)d_in[14];
    const float* p2_ain_w = (const float*)d_in[15];
    const float* p2_ain_b = (const float*)d_in[16];
    const float* p2_aout_w= (const float*)d_in[17];
    const float* p2_aout_b= (const float*)d_in[18];

    char* ws = (char*)d_ws;
    size_t off = 0;
    float* xwA = (float*)(ws + off);            off += (size_t)B_ * T_ * C_ * 4;
    float* xwB = (float*)(ws + off);            off += (size_t)B_ * T_ * C_ * 4;
    __hip_bfloat16* W1 = (__hip_bfloat16*)(ws + off);   off += (size_t)L_ * B_ * E_ * C_ * 2;
    __hip_bfloat16* W2 = (__hip_bfloat16*)(ws + off);   off += (size_t)L_ * B_ * C_ * E_ * 2;
    float* A1in  = (float*)(ws + off); off += (size_t)L_ * B_ * C_ * R_ * 4;
    float* A1out = (float*)(ws + off); off += (size_t)L_ * B_ * R_ * E_ * 4;
    float* A2in  = (float*)(ws + off); off += (size_t)L_ * B_ * E_ * R_ * 4;
    float* A2out = (float*)(ws + off); off += (size_t)L_ * B_ * R_ * C_ * 4;

    adapter_kernel<<<(L_ * C_ * R_ * B_ + 255) / 256, 256, 0, stream>>>(g, p1_ain_w, p1_ain_b, A1in, C_ * R_);
    adapter_kernel<<<(L_ * E_ * R_ * B_ + 255) / 256, 256, 0, stream>>>(g, p1_aout_w, p1_aout_b, A1out, E_ * R_);
    adapter_kernel<<<(L_ * E_ * R_ * B_ + 255) / 256, 256, 0, stream>>>(g, p2_ain_w, p2_ain_b, A2in, E_ * R_);
    adapter_kernel<<<(L_ * C_ * R_ * B_ + 255) / 256, 256, 0, stream>>>(g, p2_aout_w, p2_aout_b, A2out, C_ * R_);
    build_w1_kernel<<<(L_ * B_ * E_ * C_ + 255) / 256, 256, 0, stream>>>(p1_w, A1in, A1out, W1);
    build_w2_kernel<<<(L_ * B_ * C_ * E_ + 255) / 256, 256, 0, stream>>>(p2_w, A2in, A2out, W2);

    transpose_in_kernel<<<dim3(T_ / 64, C_ / 64, B_), 256, 0, stream>>>(x, x_mask, xwA);

    const int DILS[3] = {1, 3, 9};
    float* bufs[2] = {xwA, xwB};
    for (int l = 0; l < L_; ++l) {
        const float* src = bufs[l & 1];
        float* dst = bufs[(l & 1) ^ 1];
        ffn_fused_kernel<<<dim3(T_ / 64, B_), 512, 0, stream>>>(
            src, dst,
            dconv_w + l * C_ * K_, dconv_b + l * C_,
            ln_gamma + l * C_, ln_beta + l * C_, x_mask,
            W1 + (size_t)l * B_ * E_ * C_, p1_b + l * E_,
            W2 + (size_t)l * B_ * C_ * E_, p2_b + l * C_, DILS[l]);
    }

    transpose_out_kernel<<<dim3(T_ / 64, C_ / 64, B_), 256, 0, stream>>>(xwB, (float*)d_out);
}